// Round 5
// baseline (4861.864 us; speedup 1.0000x reference)
//
#include <hip/hip_runtime.h>
#include <stdint.h>

#define BATCH 512
#define SEQ   512
#define HID   128
#define BT    16        // batch tile per chain
#define ROWB  528       // LDS act row stride in bytes
#define NPAIR 16        // pairs of batch tiles (2 chains per block)
#define CH    8         // steps per sync chunk
#define RING  64        // ring slots (steps) per layer boundary
#define FPAD  32        // ints per flag (128B, kills false sharing)

typedef _Float16 half8 __attribute__((ext_vector_type(8)));
typedef float f32x4 __attribute__((ext_vector_type(4)));
typedef unsigned long long u64;

union UHP { uint32_t u; _Float16 h[2]; };
__device__ __forceinline__ uint32_t pack2f(float a, float b){
  UHP r; r.h[0] = (_Float16)a; r.h[1] = (_Float16)b; return r.u;
}
__device__ __forceinline__ float unpk(uint32_t u, int i){
  UHP r; r.u = u; return (float)r.h[i];
}

__device__ __forceinline__ float rcp_(float x){
#if __has_builtin(__builtin_amdgcn_rcpf)
  return __builtin_amdgcn_rcpf(x);
#else
  return 1.f / x;
#endif
}
__device__ __forceinline__ float exp2_(float x){
#if __has_builtin(__builtin_amdgcn_exp2f)
  return __builtin_amdgcn_exp2f(x);
#else
  return exp2f(x);
#endif
}
__device__ __forceinline__ float sigm(float x){ return rcp_(1.f + exp2_(x * -1.44269504f)); }
__device__ __forceinline__ float tanh_(float x){ return 1.f - 2.f * rcp_(exp2_(x * 2.88539008f) + 1.f); }

// MODE 0: x fp32 -> ring0 ; MODE 1: ring0 -> ring1 ; MODE 2: ring1 -> y fp32
template<int MODE>
__device__ __forceinline__ void run_layer(
    const float* __restrict__ Wih, const float* __restrict__ Whh,
    const float* __restrict__ bih, const float* __restrict__ bhh,
    const float* __restrict__ x, uint32_t* __restrict__ rin,
    uint32_t* __restrict__ rout, float* __restrict__ y,
    int* src_ready, int* src_done, int* dst_ready, int* dst_done,
    int b0, int ctid, bool leader, char* act0, char* act1)
{
  const int lane = ctid & 63;
  const int w    = ctid >> 6;
  const int u0   = w * 16;
  const int rm   = lane & 15;   // batch col within tile
  const int kq   = lane >> 4;   // k-quarter / acc row group

  // ---- weights -> f16 register fragments (A: 16 units x 32 k per frag)
  half8 wf[4][8];
  #pragma unroll
  for (int g = 0; g < 4; ++g){
    const int grow = g * HID + u0 + rm;
    #pragma unroll
    for (int s = 0; s < 8; ++s){
      const int k = s * 32 + kq * 8;
      const float* src = (s < 4) ? (Wih + (size_t)grow * HID + k)
                                 : (Whh + (size_t)grow * HID + (k - HID));
      const float4 aa = *(const float4*)src;
      const float4 bb = *(const float4*)(src + 4);
      half8 hh;
      hh[0]=(_Float16)aa.x; hh[1]=(_Float16)aa.y; hh[2]=(_Float16)aa.z; hh[3]=(_Float16)aa.w;
      hh[4]=(_Float16)bb.x; hh[5]=(_Float16)bb.y; hh[6]=(_Float16)bb.z; hh[7]=(_Float16)bb.w;
      wf[g][s] = hh;
    }
  }
  f32x4 bias4[4];
  #pragma unroll
  for (int g = 0; g < 4; ++g)
    #pragma unroll
    for (int r = 0; r < 4; ++r){
      const int row = g * HID + u0 + kq * 4 + r;
      bias4[g][r] = bih[row] + bhh[row];
    }

  // ---- staging thread mapping: 16 rows x 128 f16
  const int sb = ctid >> 5;   // 0..15 batch row
  const int sk = ctid & 31;   // col group
  float4 pf0; u64 pf1;

  auto issue_load = [&](int t){
    if constexpr (MODE == 0){
      pf0 = *(const float4*)(x + ((size_t)(b0 + sb) * SEQ + t) * HID + sk * 4);
    } else {
      u64* p = (u64*)(rin + ((size_t)(t & (RING-1)) * BATCH + b0 + sb) * 64 + sk * 2);
      pf1 = __hip_atomic_load(p, __ATOMIC_RELAXED, __HIP_MEMORY_SCOPE_AGENT);
    }
  };
  auto write_in = [&](char* buf){
    if constexpr (MODE == 0){
      uint2 v; v.x = pack2f(pf0.x, pf0.y); v.y = pack2f(pf0.z, pf0.w);
      *(uint2*)(buf + sb * ROWB + sk * 8) = v;
    } else {
      *(u64*)(buf + sb * ROWB + sk * 8) = pf1;
    }
  };
  auto wait_src = [&](int chunks){       // consumer: wait for producer progress
    if constexpr (MODE != 0){
      while (__hip_atomic_load(src_ready, __ATOMIC_RELAXED, __HIP_MEMORY_SCOPE_AGENT) < chunks)
        __builtin_amdgcn_s_sleep(2);
    }
  };
  auto wait_dst = [&](int chunks){       // producer: ring back-pressure
    if constexpr (MODE != 2){
      while (__hip_atomic_load(dst_done, __ATOMIC_RELAXED, __HIP_MEMORY_SCOPE_AGENT) < chunks)
        __builtin_amdgcn_s_sleep(2);
    }
  };

  // ---- prologue: stage input(0) into buf0, zero h region of buf0
  wait_src(1);
  issue_load(0);
  write_in(act0);
  if (ctid < 256)
    *(uint4*)(act0 + (ctid >> 4) * ROWB + 256 + (ctid & 15) * 16) = make_uint4(0u,0u,0u,0u);
  __syncthreads();

  f32x4 c4 = {0.f, 0.f, 0.f, 0.f};
  const int boff = rm * ROWB + kq * 16;
  int cur = 0;

  uint2 hp = {0u, 0u};     // deferred-store state (h of step t-1, f16 packed)

  for (int t = 0; t < SEQ; ++t){
    char* bc = cur ? act1 : act0;
    char* bn = cur ? act0 : act1;
    const int tn = t + 1;

    // ---- flush deferred global store for step t-1 (post-barrier: a full
    // compute phase passes before the next vmcnt(0) drain)
    if (t > 0){
      if constexpr (MODE != 2){
        const u64 hp64 = ((u64)hp.y << 32) | (u64)hp.x;
        u64* p = (u64*)(rout + ((size_t)((t-1) & (RING-1)) * BATCH + b0 + rm) * 64 + (u0 >> 1) + kq * 2);
        __hip_atomic_store(p, hp64, __ATOMIC_RELAXED, __HIP_MEMORY_SCOPE_AGENT);
      } else {
        const size_t yb = ((size_t)(t-1) * HID + u0 + kq * 4) * BATCH + b0 + rm;
        y[yb]             = unpk(hp.x, 0);
        y[yb + BATCH]     = unpk(hp.x, 1);
        y[yb + 2 * BATCH] = unpk(hp.y, 0);
        y[yb + 3 * BATCH] = unpk(hp.y, 1);
      }
    }
    // ---- flag publishes (pair leader; stores for chunk k are fully drained
    // by the barrier at end of step 8k+8 -> publish at t=8k+9)
    if (leader){
      if constexpr (MODE != 2){
        if ((t & (CH-1)) == 1 && t >= 9)
          __hip_atomic_store(dst_ready, (t-1) >> 3, __ATOMIC_RELAXED, __HIP_MEMORY_SCOPE_AGENT);
      }
      if constexpr (MODE != 0){
        if ((t & (CH-1)) == 0 && t > 0)
          __hip_atomic_store(src_done, t >> 3, __ATOMIC_RELAXED, __HIP_MEMORY_SCOPE_AGENT);
      }
    }

    if (tn < SEQ && (tn & (CH-1)) == 0) wait_src((tn >> 3) + 1);
    if ((t & (CH-1)) == 0 && t >= RING) wait_dst((t >> 3) - 7);
    if (tn < SEQ) issue_load(tn);       // global prefetch overlaps compute

    f32x4 a0 = bias4[0], a1 = bias4[1], a2 = bias4[2], a3 = bias4[3];
    #pragma unroll
    for (int s = 0; s < 8; ++s){
      const half8 bf = *(const half8*)(bc + boff + s * 64);
      a0 = __builtin_amdgcn_mfma_f32_16x16x32_f16(wf[0][s], bf, a0, 0, 0, 0);
      a1 = __builtin_amdgcn_mfma_f32_16x16x32_f16(wf[1][s], bf, a1, 0, 0, 0);
      a2 = __builtin_amdgcn_mfma_f32_16x16x32_f16(wf[2][s], bf, a2, 0, 0, 0);
      a3 = __builtin_amdgcn_mfma_f32_16x16x32_f16(wf[3][s], bf, a3, 0, 0, 0);
    }

    // elementwise fully in-register: lane holds i,f,g,o for 4 units, 1 batch col
    float hvr[4];
    #pragma unroll
    for (int r = 0; r < 4; ++r){
      const float ii = sigm(a0[r]), ff = sigm(a1[r]);
      const float gg = tanh_(a2[r]), oo = sigm(a3[r]);
      c4[r] = ff * c4[r] + ii * gg;
      hvr[r] = oo * tanh_(c4[r]);
    }
    hp.x = pack2f(hvr[0], hvr[1]);
    hp.y = pack2f(hvr[2], hvr[3]);

    // next-step operands -> other buffer; single barrier per step
    *(uint2*)(bn + rm * ROWB + 256 + u0 * 2 + kq * 8) = hp;
    if (tn < SEQ) write_in(bn);
    __syncthreads();
    cur ^= 1;
  }

  // ---- tail: flush step SEQ-1, drain, final publish
  if constexpr (MODE != 2){
    const u64 hp64 = ((u64)hp.y << 32) | (u64)hp.x;
    u64* p = (u64*)(rout + ((size_t)((SEQ-1) & (RING-1)) * BATCH + b0 + rm) * 64 + (u0 >> 1) + kq * 2);
    __hip_atomic_store(p, hp64, __ATOMIC_RELAXED, __HIP_MEMORY_SCOPE_AGENT);
  } else {
    const size_t yb = ((size_t)(SEQ-1) * HID + u0 + kq * 4) * BATCH + b0 + rm;
    y[yb]             = unpk(hp.x, 0);
    y[yb + BATCH]     = unpk(hp.x, 1);
    y[yb + 2 * BATCH] = unpk(hp.y, 0);
    y[yb + 3 * BATCH] = unpk(hp.y, 1);
  }
  __syncthreads();   // drains vmcnt: all stores of both chains complete
  if (leader){
    if constexpr (MODE != 2)
      __hip_atomic_store(dst_ready, SEQ / CH, __ATOMIC_RELAXED, __HIP_MEMORY_SCOPE_AGENT);
    if constexpr (MODE != 0)
      __hip_atomic_store(src_done, SEQ / CH, __ATOMIC_RELAXED, __HIP_MEMORY_SCOPE_AGENT);
  }
}

// Grid: 48 blocks (3 layers x 16 pairs) x 1024 threads (16 waves, 2 chains).
// NOTE: __launch_bounds__(1024) with NO min-waves arg — a 1024-thread block
// hardware-requires 4 waves/EU => VGPR cap 128, which this kernel exactly
// fits. Round 4's (1024,4) forced a 64-VGPR cap -> total spill of the 128
// weight VGPRs -> 5x regression.
__global__ __launch_bounds__(1024) void lstm_pipe(
    const float* W0i, const float* W0h, const float* b0i, const float* b0h,
    const float* W1i, const float* W1h, const float* b1i, const float* b1h,
    const float* W2i, const float* W2h, const float* b2i, const float* b2h,
    const float* x, float* y, uint32_t* ring, int* flags)
{
  const int layer = blockIdx.x / NPAIR;        // 0,1,2
  const int pair  = blockIdx.x % NPAIR;
  const int chain = threadIdx.x >> 9;          // 0,1
  const int ctid  = threadIdx.x & 511;
  const int tile  = pair * 2 + chain;
  const int b0    = tile * BT;
  const bool leader = (threadIdx.x == 0);

  __shared__ char act[2][2][BT * ROWB];        // [chain][buf]

  uint32_t* r0 = ring;                                 // boundary 0: L0 -> L1
  uint32_t* r1 = ring + (size_t)RING * BATCH * 64;     // boundary 1: L1 -> L2

  int* f0r = flags + (0 * NPAIR + pair) * FPAD;
  int* f0d = flags + (1 * NPAIR + pair) * FPAD;
  int* f1r = flags + (2 * NPAIR + pair) * FPAD;
  int* f1d = flags + (3 * NPAIR + pair) * FPAD;

  char* a0 = act[chain][0];
  char* a1 = act[chain][1];

  if (layer == 0){
    run_layer<0>(W0i, W0h, b0i, b0h, x, nullptr, r0, nullptr,
                 nullptr, nullptr, f0r, f0d, b0, ctid, leader, a0, a1);
  } else if (layer == 1){
    run_layer<1>(W1i, W1h, b1i, b1h, nullptr, r0, r1, nullptr,
                 f0r, f0d, f1r, f1d, b0, ctid, leader, a0, a1);
  } else {
    run_layer<2>(W2i, W2h, b2i, b2h, nullptr, r1, nullptr, y,
                 f1r, f1d, nullptr, nullptr, b0, ctid, leader, a0, a1);
  }
}

extern "C" void kernel_launch(void* const* d_in, const int* in_sizes, int n_in,
                              void* d_out, int out_size, void* d_ws, size_t ws_size,
                              hipStream_t stream) {
  const float* x    = (const float*)d_in[0];
  const float* Wih0 = (const float*)d_in[1];
  const float* Whh0 = (const float*)d_in[2];
  const float* bih0 = (const float*)d_in[3];
  const float* bhh0 = (const float*)d_in[4];
  const float* Wih1 = (const float*)d_in[5];
  const float* Whh1 = (const float*)d_in[6];
  const float* bih1 = (const float*)d_in[7];
  const float* bhh1 = (const float*)d_in[8];
  const float* Wih2 = (const float*)d_in[9];
  const float* Whh2 = (const float*)d_in[10];
  const float* bih2 = (const float*)d_in[11];
  const float* bhh2 = (const float*)d_in[12];

  float* out = (float*)d_out;
  uint32_t* ring = (uint32_t*)d_ws;
  const size_t ring_bytes = (size_t)2 * RING * BATCH * 64 * 4;   // 16 MiB
  int* flags = (int*)((char*)d_ws + ring_bytes);

  hipMemsetAsync(flags, 0, 4 * NPAIR * FPAD * sizeof(int), stream);

  dim3 grid(3 * NPAIR), block(1024);
  lstm_pipe<<<grid, block, 0, stream>>>(
      Wih0, Whh0, bih0, bhh0, Wih1, Whh1, bih1, bhh1, Wih2, Whh2, bih2, bhh2,
      x, out, ring, flags);
}

// Round 6
// 1045.644 us; speedup vs baseline: 4.6496x; 4.6496x over previous
//
#include <hip/hip_runtime.h>
#include <stdint.h>

#define BATCH 512
#define SEQ   512
#define HID   128
#define BT    16        // batch tile per block
#define ROWB  528       // LDS act row stride in bytes
#define NTILE 32        // BATCH/BT
#define CH    8         // steps per sync chunk
#define RING  64        // ring slots (steps) per layer boundary
#define FPAD  32        // ints per flag (128B line, kills false sharing)

typedef _Float16 half8 __attribute__((ext_vector_type(8)));
typedef float f32x4 __attribute__((ext_vector_type(4)));
typedef unsigned long long u64;

union UHP { uint32_t u; _Float16 h[2]; };
__device__ __forceinline__ uint32_t pack2f(float a, float b){
  UHP r; r.h[0] = (_Float16)a; r.h[1] = (_Float16)b; return r.u;
}
__device__ __forceinline__ float unpk(uint32_t u, int i){
  UHP r; r.u = u; return (float)r.h[i];
}

__device__ __forceinline__ float rcp_(float x){
#if __has_builtin(__builtin_amdgcn_rcpf)
  return __builtin_amdgcn_rcpf(x);
#else
  return 1.f / x;
#endif
}
__device__ __forceinline__ float exp2_(float x){
#if __has_builtin(__builtin_amdgcn_exp2f)
  return __builtin_amdgcn_exp2f(x);
#else
  return exp2f(x);
#endif
}
__device__ __forceinline__ float sigm(float x){ return rcp_(1.f + exp2_(x * -1.44269504f)); }
__device__ __forceinline__ float tanh_(float x){ return 1.f - 2.f * rcp_(exp2_(x * 2.88539008f) + 1.f); }

// MODE 0: x fp32 -> ring0 ; MODE 1: ring0 -> ring1 ; MODE 2: ring1 -> y fp32
template<int MODE>
__device__ __forceinline__ void run_layer(
    const float* __restrict__ Wih, const float* __restrict__ Whh,
    const float* __restrict__ bih, const float* __restrict__ bhh,
    const float* __restrict__ x, uint32_t* __restrict__ rin,
    uint32_t* __restrict__ rout, float* __restrict__ y,
    int* src_ready, int* src_done, int* dst_ready, int* dst_done,
    int b0, char* act0, char* act1)
{
  const int tid  = threadIdx.x;
  const int lane = tid & 63;
  const int w    = tid >> 6;
  const int u0   = w * 16;
  const int rm   = lane & 15;   // batch col within tile
  const int kq   = lane >> 4;   // k-quarter / acc row group

  // ---- weights -> f16 register fragments (A: 16 units x 32 k per frag)
  half8 wf[4][8];
  #pragma unroll
  for (int g = 0; g < 4; ++g){
    const int grow = g * HID + u0 + rm;
    #pragma unroll
    for (int s = 0; s < 8; ++s){
      const int k = s * 32 + kq * 8;
      const float* src = (s < 4) ? (Wih + (size_t)grow * HID + k)
                                 : (Whh + (size_t)grow * HID + (k - HID));
      const float4 aa = *(const float4*)src;
      const float4 bb = *(const float4*)(src + 4);
      half8 hh;
      hh[0]=(_Float16)aa.x; hh[1]=(_Float16)aa.y; hh[2]=(_Float16)aa.z; hh[3]=(_Float16)aa.w;
      hh[4]=(_Float16)bb.x; hh[5]=(_Float16)bb.y; hh[6]=(_Float16)bb.z; hh[7]=(_Float16)bb.w;
      wf[g][s] = hh;
    }
  }
  f32x4 bias4[4];
  #pragma unroll
  for (int g = 0; g < 4; ++g)
    #pragma unroll
    for (int r = 0; r < 4; ++r){
      const int row = g * HID + u0 + kq * 4 + r;
      bias4[g][r] = bih[row] + bhh[row];
    }

  // ---- staging thread mapping: 16 rows x 128 f16
  const int sb = tid >> 5;   // 0..15 batch row
  const int sk = tid & 31;   // col group
  float4 pf0; u64 pf1;

  auto issue_load = [&](int t){
    if constexpr (MODE == 0){
      pf0 = *(const float4*)(x + ((size_t)(b0 + sb) * SEQ + t) * HID + sk * 4);
    } else {
      u64* p = (u64*)(rin + ((size_t)(t & (RING-1)) * BATCH + b0 + sb) * 64 + sk * 2);
      pf1 = __hip_atomic_load(p, __ATOMIC_RELAXED, __HIP_MEMORY_SCOPE_AGENT);
    }
  };
  auto write_in = [&](char* buf){
    if constexpr (MODE == 0){
      uint2 v; v.x = pack2f(pf0.x, pf0.y); v.y = pack2f(pf0.z, pf0.w);
      *(uint2*)(buf + sb * ROWB + sk * 8) = v;
    } else {
      *(u64*)(buf + sb * ROWB + sk * 8) = pf1;
    }
  };
  auto wait_src = [&](int chunks){       // consumer: wait for producer progress
    if constexpr (MODE != 0){
      while (__hip_atomic_load(src_ready, __ATOMIC_RELAXED, __HIP_MEMORY_SCOPE_AGENT) < chunks)
        __builtin_amdgcn_s_sleep(2);
    }
  };
  auto wait_dst = [&](int chunks){       // producer: ring back-pressure
    if constexpr (MODE != 2){
      while (__hip_atomic_load(dst_done, __ATOMIC_RELAXED, __HIP_MEMORY_SCOPE_AGENT) < chunks)
        __builtin_amdgcn_s_sleep(2);
    }
  };

  // ---- prologue: stage input(0) into buf0, zero h region of buf0
  wait_src(1);
  issue_load(0);
  write_in(act0);
  if (tid < 256)
    *(uint4*)(act0 + (tid >> 4) * ROWB + 256 + (tid & 15) * 16) = make_uint4(0u,0u,0u,0u);
  __syncthreads();

  f32x4 c4 = {0.f, 0.f, 0.f, 0.f};
  const int boff = rm * ROWB + kq * 16;
  int cur = 0;

  uint2 hp = {0u, 0u};     // deferred-store state (h of step t-1, f16 packed)

  for (int t = 0; t < SEQ; ++t){
    char* bc = cur ? act1 : act0;
    char* bn = cur ? act0 : act1;
    const int tn = t + 1;

    // ---- flush deferred global store of step t-1 (issued at TOP of step:
    // the end-of-step barrier's vmcnt(0) drain finds it long since ack'd)
    if (t > 0){
      if constexpr (MODE != 2){
        const u64 hp64 = ((u64)hp.y << 32) | (u64)hp.x;
        u64* p = (u64*)(rout + ((size_t)((t-1) & (RING-1)) * BATCH + b0 + rm) * 64 + (u0 >> 1) + kq * 2);
        __hip_atomic_store(p, hp64, __ATOMIC_RELAXED, __HIP_MEMORY_SCOPE_AGENT);
      } else {
        const size_t yb = ((size_t)(t-1) * HID + u0 + kq * 4) * BATCH + b0 + rm;
        y[yb]             = unpk(hp.x, 0);
        y[yb + BATCH]     = unpk(hp.x, 1);
        y[yb + 2 * BATCH] = unpk(hp.y, 0);
        y[yb + 3 * BATCH] = unpk(hp.y, 1);
      }
    }
    // ---- flag publishes: stores of chunk k (steps 8k..8k+7) are issued by
    // step 8k+8 and drained by its end-of-step barrier -> publish at t=8k+9.
    if (tid == 0){
      if constexpr (MODE != 2){
        if ((t & (CH-1)) == 1 && t >= 9){
          __threadfence();
          __hip_atomic_store(dst_ready, (t-1) >> 3, __ATOMIC_RELAXED, __HIP_MEMORY_SCOPE_AGENT);
        }
      }
      if constexpr (MODE != 0){
        if ((t & (CH-1)) == 0 && t > 0)
          __hip_atomic_store(src_done, t >> 3, __ATOMIC_RELAXED, __HIP_MEMORY_SCOPE_AGENT);
      }
    }

    if (tn < SEQ && (tn & (CH-1)) == 0) wait_src((tn >> 3) + 1);
    if ((t & (CH-1)) == 0 && t >= RING) wait_dst((t >> 3) - 7);
    if (tn < SEQ) issue_load(tn);       // global prefetch overlaps compute

    f32x4 a0 = bias4[0], a1 = bias4[1], a2 = bias4[2], a3 = bias4[3];
    #pragma unroll
    for (int s = 0; s < 8; ++s){
      const half8 bf = *(const half8*)(bc + boff + s * 64);
      a0 = __builtin_amdgcn_mfma_f32_16x16x32_f16(wf[0][s], bf, a0, 0, 0, 0);
      a1 = __builtin_amdgcn_mfma_f32_16x16x32_f16(wf[1][s], bf, a1, 0, 0, 0);
      a2 = __builtin_amdgcn_mfma_f32_16x16x32_f16(wf[2][s], bf, a2, 0, 0, 0);
      a3 = __builtin_amdgcn_mfma_f32_16x16x32_f16(wf[3][s], bf, a3, 0, 0, 0);
    }

    // elementwise fully in-register: lane holds i,f,g,o for 4 units, 1 batch col
    float hvr[4];
    #pragma unroll
    for (int r = 0; r < 4; ++r){
      const float ii = sigm(a0[r]), ff = sigm(a1[r]);
      const float gg = tanh_(a2[r]), oo = sigm(a3[r]);
      c4[r] = ff * c4[r] + ii * gg;
      hvr[r] = oo * tanh_(c4[r]);
    }
    hp.x = pack2f(hvr[0], hvr[1]);
    hp.y = pack2f(hvr[2], hvr[3]);

    // next-step operands -> other buffer; single barrier per step
    *(uint2*)(bn + rm * ROWB + 256 + u0 * 2 + kq * 8) = hp;
    if (tn < SEQ) write_in(bn);
    __syncthreads();
    cur ^= 1;
  }

  // ---- tail: flush step SEQ-1, drain, final publish
  if constexpr (MODE != 2){
    const u64 hp64 = ((u64)hp.y << 32) | (u64)hp.x;
    u64* p = (u64*)(rout + ((size_t)((SEQ-1) & (RING-1)) * BATCH + b0 + rm) * 64 + (u0 >> 1) + kq * 2);
    __hip_atomic_store(p, hp64, __ATOMIC_RELAXED, __HIP_MEMORY_SCOPE_AGENT);
  } else {
    const size_t yb = ((size_t)(SEQ-1) * HID + u0 + kq * 4) * BATCH + b0 + rm;
    y[yb]             = unpk(hp.x, 0);
    y[yb + BATCH]     = unpk(hp.x, 1);
    y[yb + 2 * BATCH] = unpk(hp.y, 0);
    y[yb + 3 * BATCH] = unpk(hp.y, 1);
  }
  __syncthreads();   // drains vmcnt: all stores complete
  if (tid == 0){
    if constexpr (MODE != 2){
      __threadfence();
      __hip_atomic_store(dst_ready, SEQ / CH, __ATOMIC_RELAXED, __HIP_MEMORY_SCOPE_AGENT);
    }
    if constexpr (MODE != 0)
      __hip_atomic_store(src_done, SEQ / CH, __ATOMIC_RELAXED, __HIP_MEMORY_SCOPE_AGENT);
  }
}

// Grid: 96 blocks (3 layers x 32 tiles) x 512 threads. (512,2) is the PROVEN
// codegen shape: 128 arch VGPRs, weights register-resident, zero spill.
// 1024-thread variants (rounds 4-5) spilled: backend caps them at 64 VGPRs.
__global__ __launch_bounds__(512, 2) void lstm_pipe(
    const float* W0i, const float* W0h, const float* b0i, const float* b0h,
    const float* W1i, const float* W1h, const float* b1i, const float* b1h,
    const float* W2i, const float* W2h, const float* b2i, const float* b2h,
    const float* x, float* y, uint32_t* ring, int* flags)
{
  const int layer = blockIdx.x >> 5;   // 0,1,2
  const int tile  = blockIdx.x & 31;
  const int b0    = tile * BT;

  __shared__ char act[2][BT * ROWB];

  uint32_t* r0 = ring;                                 // boundary 0: L0 -> L1
  uint32_t* r1 = ring + (size_t)RING * BATCH * 64;     // boundary 1: L1 -> L2

  // flags: 4 regions x 32 tiles, each flag on its own 128B line
  int* p0 = flags + (0 * NTILE + tile) * FPAD;   // ready, boundary 0
  int* p1 = flags + (1 * NTILE + tile) * FPAD;   // ready, boundary 1
  int* c0 = flags + (2 * NTILE + tile) * FPAD;   // done,  boundary 0
  int* c1 = flags + (3 * NTILE + tile) * FPAD;   // done,  boundary 1

  if (layer == 0){
    run_layer<0>(W0i, W0h, b0i, b0h, x, nullptr, r0, nullptr,
                 nullptr, nullptr, p0, c0, b0, act[0], act[1]);
  } else if (layer == 1){
    run_layer<1>(W1i, W1h, b1i, b1h, nullptr, r0, r1, nullptr,
                 p0, c0, p1, c1, b0, act[0], act[1]);
  } else {
    run_layer<2>(W2i, W2h, b2i, b2h, nullptr, r1, nullptr, y,
                 p1, c1, nullptr, nullptr, b0, act[0], act[1]);
  }
}

extern "C" void kernel_launch(void* const* d_in, const int* in_sizes, int n_in,
                              void* d_out, int out_size, void* d_ws, size_t ws_size,
                              hipStream_t stream) {
  const float* x    = (const float*)d_in[0];
  const float* Wih0 = (const float*)d_in[1];
  const float* Whh0 = (const float*)d_in[2];
  const float* bih0 = (const float*)d_in[3];
  const float* bhh0 = (const float*)d_in[4];
  const float* Wih1 = (const float*)d_in[5];
  const float* Whh1 = (const float*)d_in[6];
  const float* bih1 = (const float*)d_in[7];
  const float* bhh1 = (const float*)d_in[8];
  const float* Wih2 = (const float*)d_in[9];
  const float* Whh2 = (const float*)d_in[10];
  const float* bih2 = (const float*)d_in[11];
  const float* bhh2 = (const float*)d_in[12];

  float* out = (float*)d_out;
  uint32_t* ring = (uint32_t*)d_ws;
  const size_t ring_bytes = (size_t)2 * RING * BATCH * 64 * 4;   // 16 MiB
  int* flags = (int*)((char*)d_ws + ring_bytes);

  hipMemsetAsync(flags, 0, 4 * NTILE * FPAD * sizeof(int), stream);

  dim3 grid(3 * NTILE), block(512);
  lstm_pipe<<<grid, block, 0, stream>>>(
      Wih0, Whh0, bih0, bhh0, Wih1, Whh1, bih1, bhh1, Wih2, Whh2, bih2, bhh2,
      x, out, ring, flags);
}

// Round 7
// 1010.265 us; speedup vs baseline: 4.8125x; 1.0350x over previous
//
#include <hip/hip_runtime.h>
#include <stdint.h>

#define BATCH 512
#define SEQ   512
#define HID   128
#define BT    16        // batch tile per block
#define ROWB  528       // LDS act row stride in bytes
#define NTILE 32        // BATCH/BT
#define CH    8         // steps per done-chunk (back-pressure only)
#define RING  64        // ring slots (steps) per layer boundary
#define FPAD  32        // ints per flag (128B line, kills false sharing)

typedef _Float16 half8 __attribute__((ext_vector_type(8)));
typedef float f32x4 __attribute__((ext_vector_type(4)));
typedef unsigned long long u64;

union UHP { uint32_t u; _Float16 h[2]; };
__device__ __forceinline__ uint32_t pack2f(float a, float b){
  UHP r; r.h[0] = (_Float16)a; r.h[1] = (_Float16)b; return r.u;
}
__device__ __forceinline__ float unpk(uint32_t u, int i){
  UHP r; r.u = u; return (float)r.h[i];
}

__device__ __forceinline__ float rcp_(float x){
#if __has_builtin(__builtin_amdgcn_rcpf)
  return __builtin_amdgcn_rcpf(x);
#else
  return 1.f / x;
#endif
}
__device__ __forceinline__ float exp2_(float x){
#if __has_builtin(__builtin_amdgcn_exp2f)
  return __builtin_amdgcn_exp2f(x);
#else
  return exp2f(x);
#endif
}
__device__ __forceinline__ float sigm(float x){ return rcp_(1.f + exp2_(x * -1.44269504f)); }
__device__ __forceinline__ float tanh_(float x){ return 1.f - 2.f * rcp_(exp2_(x * 2.88539008f) + 1.f); }

// MODE 0: x fp32 -> ring0 ; MODE 1: ring0 -> ring1 ; MODE 2: ring1 -> y fp32
// Sync protocol (per boundary, per tile):
//   ready flag: monotone int, = number of producer steps visible at the
//     coherent point. Producer publishes (t-1) at the top of step t: step
//     t-2's stores were issued at top of t-1 and drained by its end-of-step
//     barrier, so steps <= t-2 are globally visible. Published EVERY step ->
//     consumer sees a continuous stream; propagation latency is a constant
//     pipeline offset, not a per-chunk stall.
//   done flag: chunk counter (CH steps), back-pressure only (lag << RING).
template<int MODE>
__device__ __forceinline__ void run_layer(
    const float* __restrict__ Wih, const float* __restrict__ Whh,
    const float* __restrict__ bih, const float* __restrict__ bhh,
    const float* __restrict__ x, uint32_t* __restrict__ rin,
    uint32_t* __restrict__ rout, float* __restrict__ y,
    int* src_ready, int* src_done, int* dst_ready, int* dst_done,
    int b0, char* act0, char* act1)
{
  const int tid  = threadIdx.x;
  const int lane = tid & 63;
  const int w    = tid >> 6;
  const int u0   = w * 16;
  const int rm   = lane & 15;   // batch col within tile
  const int kq   = lane >> 4;   // k-quarter / acc row group

  // ---- weights -> f16 register fragments (A: 16 units x 32 k per frag)
  half8 wf[4][8];
  #pragma unroll
  for (int g = 0; g < 4; ++g){
    const int grow = g * HID + u0 + rm;
    #pragma unroll
    for (int s = 0; s < 8; ++s){
      const int k = s * 32 + kq * 8;
      const float* src = (s < 4) ? (Wih + (size_t)grow * HID + k)
                                 : (Whh + (size_t)grow * HID + (k - HID));
      const float4 aa = *(const float4*)src;
      const float4 bb = *(const float4*)(src + 4);
      half8 hh;
      hh[0]=(_Float16)aa.x; hh[1]=(_Float16)aa.y; hh[2]=(_Float16)aa.z; hh[3]=(_Float16)aa.w;
      hh[4]=(_Float16)bb.x; hh[5]=(_Float16)bb.y; hh[6]=(_Float16)bb.z; hh[7]=(_Float16)bb.w;
      wf[g][s] = hh;
    }
  }
  f32x4 bias4[4];
  #pragma unroll
  for (int g = 0; g < 4; ++g)
    #pragma unroll
    for (int r = 0; r < 4; ++r){
      const int row = g * HID + u0 + kq * 4 + r;
      bias4[g][r] = bih[row] + bhh[row];
    }

  // ---- staging thread mapping: 16 rows x 128 f16
  const int sb = tid >> 5;   // 0..15 batch row
  const int sk = tid & 31;   // col group
  float4 pf0; u64 pf1;

  auto issue_load = [&](int t){
    if constexpr (MODE == 0){
      pf0 = *(const float4*)(x + ((size_t)(b0 + sb) * SEQ + t) * HID + sk * 4);
    } else {
      u64* p = (u64*)(rin + ((size_t)(t & (RING-1)) * BATCH + b0 + sb) * 64 + sk * 2);
      pf1 = __hip_atomic_load(p, __ATOMIC_RELAXED, __HIP_MEMORY_SCOPE_AGENT);
    }
  };
  auto write_in = [&](char* buf){
    if constexpr (MODE == 0){
      uint2 v; v.x = pack2f(pf0.x, pf0.y); v.y = pack2f(pf0.z, pf0.w);
      *(uint2*)(buf + sb * ROWB + sk * 8) = v;
    } else {
      *(u64*)(buf + sb * ROWB + sk * 8) = pf1;
    }
  };

  int seen = 0;   // cached value of src_ready
  auto ensure_src = [&](int s){   // need steps <= s visible: flag >= s+1
    if constexpr (MODE != 0){
      if (seen < s + 1){
        seen = __hip_atomic_load(src_ready, __ATOMIC_RELAXED, __HIP_MEMORY_SCOPE_AGENT);
        while (seen < s + 1){
          __builtin_amdgcn_s_sleep(2);
          seen = __hip_atomic_load(src_ready, __ATOMIC_RELAXED, __HIP_MEMORY_SCOPE_AGENT);
        }
      }
    }
  };
  auto wait_dst = [&](int chunks){   // producer: ring back-pressure (rarely binds)
    if constexpr (MODE != 2){
      while (__hip_atomic_load(dst_done, __ATOMIC_RELAXED, __HIP_MEMORY_SCOPE_AGENT) < chunks)
        __builtin_amdgcn_s_sleep(2);
    }
  };

  // ---- prologue: stage input(0) into buf0, zero h region of buf0
  ensure_src(0);
  issue_load(0);
  write_in(act0);
  if (tid < 256)
    *(uint4*)(act0 + (tid >> 4) * ROWB + 256 + (tid & 15) * 16) = make_uint4(0u,0u,0u,0u);
  __syncthreads();

  f32x4 c4 = {0.f, 0.f, 0.f, 0.f};
  const int boff = rm * ROWB + kq * 16;
  int cur = 0;

  uint2 hp = {0u, 0u};     // deferred-store state (h of step t-1, f16 packed)

  for (int t = 0; t < SEQ; ++t){
    char* bc = cur ? act1 : act0;
    char* bn = cur ? act0 : act1;
    const int tn = t + 1;

    // ---- flush deferred global store of step t-1 (issued at TOP of step:
    // end-of-step barrier drain finds it long since ack'd)
    if (t > 0){
      if constexpr (MODE != 2){
        const u64 hp64 = ((u64)hp.y << 32) | (u64)hp.x;
        u64* p = (u64*)(rout + ((size_t)((t-1) & (RING-1)) * BATCH + b0 + rm) * 64 + (u0 >> 1) + kq * 2);
        __hip_atomic_store(p, hp64, __ATOMIC_RELAXED, __HIP_MEMORY_SCOPE_AGENT);
      } else {
        const size_t yb = ((size_t)(t-1) * HID + u0 + kq * 4) * BATCH + b0 + rm;
        y[yb]             = unpk(hp.x, 0);
        y[yb + BATCH]     = unpk(hp.x, 1);
        y[yb + 2 * BATCH] = unpk(hp.y, 0);
        y[yb + 3 * BATCH] = unpk(hp.y, 1);
      }
    }
    // ---- continuous ready publish: steps <= t-2 are visible (their stores
    // were drained by the end-of-step barrier of step t-1). No fence needed:
    // the barrier's vmcnt(0) drain already completed them at the coherent point.
    if (tid == 0){
      if constexpr (MODE != 2){
        if (t >= 2)
          __hip_atomic_store(dst_ready, t - 1, __ATOMIC_RELAXED, __HIP_MEMORY_SCOPE_AGENT);
      }
      if constexpr (MODE != 0){
        if ((t & (CH-1)) == 0 && t > 0)
          __hip_atomic_store(src_done, t >> 3, __ATOMIC_RELAXED, __HIP_MEMORY_SCOPE_AGENT);
      }
    }
    if ((t & (CH-1)) == 0 && t >= RING) wait_dst((t >> 3) - 7);

    if (tn < SEQ){
      ensure_src(tn);        // typically satisfied by cached/streamed flag
      issue_load(tn);        // global prefetch overlaps compute
    }

    f32x4 a0 = bias4[0], a1 = bias4[1], a2 = bias4[2], a3 = bias4[3];
    #pragma unroll
    for (int s = 0; s < 8; ++s){
      const half8 bf = *(const half8*)(bc + boff + s * 64);
      a0 = __builtin_amdgcn_mfma_f32_16x16x32_f16(wf[0][s], bf, a0, 0, 0, 0);
      a1 = __builtin_amdgcn_mfma_f32_16x16x32_f16(wf[1][s], bf, a1, 0, 0, 0);
      a2 = __builtin_amdgcn_mfma_f32_16x16x32_f16(wf[2][s], bf, a2, 0, 0, 0);
      a3 = __builtin_amdgcn_mfma_f32_16x16x32_f16(wf[3][s], bf, a3, 0, 0, 0);
    }

    // elementwise fully in-register: lane holds i,f,g,o for 4 units, 1 batch col
    float hvr[4];
    #pragma unroll
    for (int r = 0; r < 4; ++r){
      const float ii = sigm(a0[r]), ff = sigm(a1[r]);
      const float gg = tanh_(a2[r]), oo = sigm(a3[r]);
      c4[r] = ff * c4[r] + ii * gg;
      hvr[r] = oo * tanh_(c4[r]);
    }
    hp.x = pack2f(hvr[0], hvr[1]);
    hp.y = pack2f(hvr[2], hvr[3]);

    // next-step operands -> other buffer; single barrier per step
    *(uint2*)(bn + rm * ROWB + 256 + u0 * 2 + kq * 8) = hp;
    if (tn < SEQ) write_in(bn);
    __syncthreads();
    cur ^= 1;
  }

  // ---- tail: flush step SEQ-1, drain, final publishes
  if constexpr (MODE != 2){
    const u64 hp64 = ((u64)hp.y << 32) | (u64)hp.x;
    u64* p = (u64*)(rout + ((size_t)((SEQ-1) & (RING-1)) * BATCH + b0 + rm) * 64 + (u0 >> 1) + kq * 2);
    __hip_atomic_store(p, hp64, __ATOMIC_RELAXED, __HIP_MEMORY_SCOPE_AGENT);
  } else {
    const size_t yb = ((size_t)(SEQ-1) * HID + u0 + kq * 4) * BATCH + b0 + rm;
    y[yb]             = unpk(hp.x, 0);
    y[yb + BATCH]     = unpk(hp.x, 1);
    y[yb + 2 * BATCH] = unpk(hp.y, 0);
    y[yb + 3 * BATCH] = unpk(hp.y, 1);
  }
  __syncthreads();   // drains vmcnt: all stores complete
  if (tid == 0){
    if constexpr (MODE != 2)
      __hip_atomic_store(dst_ready, SEQ, __ATOMIC_RELAXED, __HIP_MEMORY_SCOPE_AGENT);
    if constexpr (MODE != 0)
      __hip_atomic_store(src_done, SEQ / CH, __ATOMIC_RELAXED, __HIP_MEMORY_SCOPE_AGENT);
  }
}

// Grid: 96 blocks (3 layers x 32 tiles) x 512 threads. (512,2) is the PROVEN
// codegen shape: 128 arch VGPRs, weights register-resident, zero spill.
__global__ __launch_bounds__(512, 2) void lstm_pipe(
    const float* W0i, const float* W0h, const float* b0i, const float* b0h,
    const float* W1i, const float* W1h, const float* b1i, const float* b1h,
    const float* W2i, const float* W2h, const float* b2i, const float* b2h,
    const float* x, float* y, uint32_t* ring, int* flags)
{
  const int layer = blockIdx.x >> 5;   // 0,1,2
  const int tile  = blockIdx.x & 31;
  const int b0    = tile * BT;

  __shared__ char act[2][BT * ROWB];

  uint32_t* r0 = ring;                                 // boundary 0: L0 -> L1
  uint32_t* r1 = ring + (size_t)RING * BATCH * 64;     // boundary 1: L1 -> L2

  // flags: 4 regions x 32 tiles, each flag on its own 128B line
  int* p0 = flags + (0 * NTILE + tile) * FPAD;   // ready, boundary 0
  int* p1 = flags + (1 * NTILE + tile) * FPAD;   // ready, boundary 1
  int* c0 = flags + (2 * NTILE + tile) * FPAD;   // done,  boundary 0
  int* c1 = flags + (3 * NTILE + tile) * FPAD;   // done,  boundary 1

  if (layer == 0){
    run_layer<0>(W0i, W0h, b0i, b0h, x, nullptr, r0, nullptr,
                 nullptr, nullptr, p0, c0, b0, act[0], act[1]);
  } else if (layer == 1){
    run_layer<1>(W1i, W1h, b1i, b1h, nullptr, r0, r1, nullptr,
                 p0, c0, p1, c1, b0, act[0], act[1]);
  } else {
    run_layer<2>(W2i, W2h, b2i, b2h, nullptr, r1, nullptr, y,
                 p1, c1, nullptr, nullptr, b0, act[0], act[1]);
  }
}

extern "C" void kernel_launch(void* const* d_in, const int* in_sizes, int n_in,
                              void* d_out, int out_size, void* d_ws, size_t ws_size,
                              hipStream_t stream) {
  const float* x    = (const float*)d_in[0];
  const float* Wih0 = (const float*)d_in[1];
  const float* Whh0 = (const float*)d_in[2];
  const float* bih0 = (const float*)d_in[3];
  const float* bhh0 = (const float*)d_in[4];
  const float* Wih1 = (const float*)d_in[5];
  const float* Whh1 = (const float*)d_in[6];
  const float* bih1 = (const float*)d_in[7];
  const float* bhh1 = (const float*)d_in[8];
  const float* Wih2 = (const float*)d_in[9];
  const float* Whh2 = (const float*)d_in[10];
  const float* bih2 = (const float*)d_in[11];
  const float* bhh2 = (const float*)d_in[12];

  float* out = (float*)d_out;
  uint32_t* ring = (uint32_t*)d_ws;
  const size_t ring_bytes = (size_t)2 * RING * BATCH * 64 * 4;   // 16 MiB
  int* flags = (int*)((char*)d_ws + ring_bytes);

  hipMemsetAsync(flags, 0, 4 * NTILE * FPAD * sizeof(int), stream);

  dim3 grid(3 * NTILE), block(512);
  lstm_pipe<<<grid, block, 0, stream>>>(
      Wih0, Whh0, bih0, bhh0, Wih1, Whh1, bih1, bhh1, Wih2, Whh2, bih2, bhh2,
      x, out, ring, flags);
}

// Round 8
// 657.917 us; speedup vs baseline: 7.3898x; 1.5356x over previous
//
#include <hip/hip_runtime.h>
#include <stdint.h>

#define BATCH 512
#define SEQ   512
#define HID   128
#define BT    16        // batch tile per block
#define ROWB  528       // LDS act row stride in bytes
#define NTILE 32        // BATCH/BT
#define CH    8         // steps per done-chunk (back-pressure only)
#define RING  64        // ring slots (steps) per layer boundary
#define FPAD  32        // ints per flag (128B line, kills false sharing)
#define SKEW  8         // startup lag consumers establish vs producer

typedef _Float16 half8 __attribute__((ext_vector_type(8)));
typedef float f32x4 __attribute__((ext_vector_type(4)));
typedef unsigned long long u64;

union UHP { uint32_t u; _Float16 h[2]; };
__device__ __forceinline__ uint32_t pack2f(float a, float b){
  UHP r; r.h[0] = (_Float16)a; r.h[1] = (_Float16)b; return r.u;
}
__device__ __forceinline__ float unpk(uint32_t u, int i){
  UHP r; r.u = u; return (float)r.h[i];
}

__device__ __forceinline__ float rcp_(float x){
#if __has_builtin(__builtin_amdgcn_rcpf)
  return __builtin_amdgcn_rcpf(x);
#else
  return 1.f / x;
#endif
}
__device__ __forceinline__ float exp2_(float x){
#if __has_builtin(__builtin_amdgcn_exp2f)
  return __builtin_amdgcn_exp2f(x);
#else
  return exp2f(x);
#endif
}
__device__ __forceinline__ float sigm(float x){ return rcp_(1.f + exp2_(x * -1.44269504f)); }
__device__ __forceinline__ float tanh_(float x){ return 1.f - 2.f * rcp_(exp2_(x * 2.88539008f) + 1.f); }

__device__ __forceinline__ int aload(const int* p){
  return __hip_atomic_load(p, __ATOMIC_RELAXED, __HIP_MEMORY_SCOPE_AGENT);
}

// MODE 0: x fp32 -> ring0 ; MODE 1: ring0 -> ring1 ; MODE 2: ring1 -> y fp32
// Latency-hiding scheme (the round-8 change):
//  * ready-flag poll is SOFTWARE-PIPELINED: step t USES the flag value whose
//    load was issued at step t-1 (its waitcnt is covered by a full step of
//    compute + the pre-barrier drain), then issues the next load. Blocking
//    spin only if the stale value is insufficient (rare: SKEW-step lag).
//  * ring/x data prefetch is 2 steps deep (pf_cur/pf_nxt): load(t+2) issued
//    at t, staged into LDS at t+1, consumed at t+2.
//  * back-pressure uses a cached done value, refreshed (blocking) only when
//    the cached bound is violated.
template<int MODE>
__device__ __forceinline__ void run_layer(
    const float* __restrict__ Wih, const float* __restrict__ Whh,
    const float* __restrict__ bih, const float* __restrict__ bhh,
    const float* __restrict__ x, uint32_t* __restrict__ rin,
    uint32_t* __restrict__ rout, float* __restrict__ y,
    int* src_ready, int* src_done, int* dst_ready, int* dst_done,
    int b0, char* act0, char* act1)
{
  const int tid  = threadIdx.x;
  const int lane = tid & 63;
  const int w    = tid >> 6;
  const int u0   = w * 16;
  const int rm   = lane & 15;   // batch col within tile
  const int kq   = lane >> 4;   // k-quarter / acc row group

  // ---- weights -> f16 register fragments (A: 16 units x 32 k per frag)
  half8 wf[4][8];
  #pragma unroll
  for (int g = 0; g < 4; ++g){
    const int grow = g * HID + u0 + rm;
    #pragma unroll
    for (int s = 0; s < 8; ++s){
      const int k = s * 32 + kq * 8;
      const float* src = (s < 4) ? (Wih + (size_t)grow * HID + k)
                                 : (Whh + (size_t)grow * HID + (k - HID));
      const float4 aa = *(const float4*)src;
      const float4 bb = *(const float4*)(src + 4);
      half8 hh;
      hh[0]=(_Float16)aa.x; hh[1]=(_Float16)aa.y; hh[2]=(_Float16)aa.z; hh[3]=(_Float16)aa.w;
      hh[4]=(_Float16)bb.x; hh[5]=(_Float16)bb.y; hh[6]=(_Float16)bb.z; hh[7]=(_Float16)bb.w;
      wf[g][s] = hh;
    }
  }
  f32x4 bias4[4];
  #pragma unroll
  for (int g = 0; g < 4; ++g)
    #pragma unroll
    for (int r = 0; r < 4; ++r){
      const int row = g * HID + u0 + kq * 4 + r;
      bias4[g][r] = bih[row] + bhh[row];
    }

  // ---- staging thread mapping: 16 rows x 128 f16
  const int sb = tid >> 5;   // 0..15 batch row
  const int sk = tid & 31;   // col group

  auto xaddr = [&](int t){
    return (const float4*)(x + ((size_t)(b0 + sb) * SEQ + t) * HID + sk * 4);
  };
  auto raddr = [&](int t){
    return (u64*)(rin + ((size_t)(t & (RING-1)) * BATCH + b0 + sb) * 64 + sk * 2);
  };

  float4 pfa, pfb;   // MODE 0: x prefetch (cur / nxt)
  u64    pga = 0, pgb = 0;   // MODE 1/2: ring prefetch (cur / nxt)

  int fseen = 0, fpend = 0, dseen = 0;

  // ---- prologue: establish SKEW-step lag, stage data(0), preload data(1)
  if constexpr (MODE != 0){
    fseen = aload(src_ready);
    while (fseen < SKEW){ __builtin_amdgcn_s_sleep(8); fseen = aload(src_ready); }
  }
  if constexpr (MODE == 0){
    const float4 v = *xaddr(0);
    uint2 p; p.x = pack2f(v.x, v.y); p.y = pack2f(v.z, v.w);
    *(uint2*)(act0 + sb * ROWB + sk * 8) = p;
    pfa = *xaddr(1);
  } else {
    const u64 v = __hip_atomic_load(raddr(0), __ATOMIC_RELAXED, __HIP_MEMORY_SCOPE_AGENT);
    *(u64*)(act0 + sb * ROWB + sk * 8) = v;
    pga = __hip_atomic_load(raddr(1), __ATOMIC_RELAXED, __HIP_MEMORY_SCOPE_AGENT);
    fpend = aload(src_ready);   // stream the flag pipeline
  }
  if (tid < 256)
    *(uint4*)(act0 + (tid >> 4) * ROWB + 256 + (tid & 15) * 16) = make_uint4(0u,0u,0u,0u);
  __syncthreads();

  f32x4 c4 = {0.f, 0.f, 0.f, 0.f};
  const int boff = rm * ROWB + kq * 16;
  int cur = 0;

  uint2 hp = {0u, 0u};     // deferred-store state (h of step t-1, f16 packed)

  for (int t = 0; t < SEQ; ++t){
    char* bc = cur ? act1 : act0;
    char* bn = cur ? act0 : act1;
    const int tn   = t + 1;
    const int tpre = t + 2;

    // ---- flush deferred global store of h(t-1) (issued at TOP of step:
    // end-of-step barrier drain finds it long since ack'd)
    if (t > 0){
      if constexpr (MODE != 2){
        const u64 hp64 = ((u64)hp.y << 32) | (u64)hp.x;
        u64* p = (u64*)(rout + ((size_t)((t-1) & (RING-1)) * BATCH + b0 + rm) * 64 + (u0 >> 1) + kq * 2);
        __hip_atomic_store(p, hp64, __ATOMIC_RELAXED, __HIP_MEMORY_SCOPE_AGENT);
      } else {
        const size_t yb = ((size_t)(t-1) * HID + u0 + kq * 4) * BATCH + b0 + rm;
        y[yb]             = unpk(hp.x, 0);
        y[yb + BATCH]     = unpk(hp.x, 1);
        y[yb + 2 * BATCH] = unpk(hp.y, 0);
        y[yb + 3 * BATCH] = unpk(hp.y, 1);
      }
    }
    // ---- continuous ready publish: steps <= t-2 are visible (their stores
    // were drained by the end-of-step barrier of step t-1).
    if (tid == 0){
      if constexpr (MODE != 2){
        if (t >= 2)
          __hip_atomic_store(dst_ready, t - 1, __ATOMIC_RELAXED, __HIP_MEMORY_SCOPE_AGENT);
      }
      if constexpr (MODE != 0){
        if ((t & (CH-1)) == 0 && t > 0)
          __hip_atomic_store(src_done, t >> 3, __ATOMIC_RELAXED, __HIP_MEMORY_SCOPE_AGENT);
      }
    }
    // ---- back-pressure: cached; blocking refresh only if bound violated
    if constexpr (MODE != 2){
      if ((t & (CH-1)) == 0 && t >= RING){
        const int need = (t >> 3) - 7;
        if (dseen < need){
          dseen = aload(dst_done);
          while (dseen < need){ __builtin_amdgcn_s_sleep(8); dseen = aload(dst_done); }
        }
      }
    }
    // ---- pipelined flag check + 2-deep data prefetch issue
    if constexpr (MODE != 0){
      const int fnew = fpend;            // waitcnt covered by previous step
      if (fnew > fseen) fseen = fnew;
      fpend = aload(src_ready);          // issue for next step
      if (tpre < SEQ && fseen < tpre + 1){
        fseen = aload(src_ready);        // rare blocking path
        while (fseen < tpre + 1){ __builtin_amdgcn_s_sleep(2); fseen = aload(src_ready); }
      }
    }
    if (tpre < SEQ){
      if constexpr (MODE == 0) pfb = *xaddr(tpre);
      else pgb = __hip_atomic_load(raddr(tpre), __ATOMIC_RELAXED, __HIP_MEMORY_SCOPE_AGENT);
    }

    // ---- gate GEMM (K=256 fused: x|h), acc init = bias
    f32x4 a0 = bias4[0], a1 = bias4[1], a2 = bias4[2], a3 = bias4[3];
    #pragma unroll
    for (int s = 0; s < 8; ++s){
      const half8 bf = *(const half8*)(bc + boff + s * 64);
      a0 = __builtin_amdgcn_mfma_f32_16x16x32_f16(wf[0][s], bf, a0, 0, 0, 0);
      a1 = __builtin_amdgcn_mfma_f32_16x16x32_f16(wf[1][s], bf, a1, 0, 0, 0);
      a2 = __builtin_amdgcn_mfma_f32_16x16x32_f16(wf[2][s], bf, a2, 0, 0, 0);
      a3 = __builtin_amdgcn_mfma_f32_16x16x32_f16(wf[3][s], bf, a3, 0, 0, 0);
    }

    // elementwise fully in-register: lane holds i,f,g,o for 4 units, 1 batch col
    float hvr[4];
    #pragma unroll
    for (int r = 0; r < 4; ++r){
      const float ii = sigm(a0[r]), ff = sigm(a1[r]);
      const float gg = tanh_(a2[r]), oo = sigm(a3[r]);
      c4[r] = ff * c4[r] + ii * gg;
      hvr[r] = oo * tanh_(c4[r]);
    }
    hp.x = pack2f(hvr[0], hvr[1]);
    hp.y = pack2f(hvr[2], hvr[3]);

    // ---- next-step operands -> other buffer; single barrier per step
    *(uint2*)(bn + rm * ROWB + 256 + u0 * 2 + kq * 8) = hp;
    if (tn < SEQ){
      if constexpr (MODE == 0){
        uint2 p; p.x = pack2f(pfa.x, pfa.y); p.y = pack2f(pfa.z, pfa.w);
        *(uint2*)(bn + sb * ROWB + sk * 8) = p;
      } else {
        *(u64*)(bn + sb * ROWB + sk * 8) = pga;
      }
    }
    __syncthreads();
    pfa = pfb; pga = pgb;
    cur ^= 1;
  }

  // ---- tail: flush step SEQ-1, drain, final publishes
  if constexpr (MODE != 2){
    const u64 hp64 = ((u64)hp.y << 32) | (u64)hp.x;
    u64* p = (u64*)(rout + ((size_t)((SEQ-1) & (RING-1)) * BATCH + b0 + rm) * 64 + (u0 >> 1) + kq * 2);
    __hip_atomic_store(p, hp64, __ATOMIC_RELAXED, __HIP_MEMORY_SCOPE_AGENT);
  } else {
    const size_t yb = ((size_t)(SEQ-1) * HID + u0 + kq * 4) * BATCH + b0 + rm;
    y[yb]             = unpk(hp.x, 0);
    y[yb + BATCH]     = unpk(hp.x, 1);
    y[yb + 2 * BATCH] = unpk(hp.y, 0);
    y[yb + 3 * BATCH] = unpk(hp.y, 1);
  }
  __syncthreads();   // drains vmcnt: all stores complete
  if (tid == 0){
    if constexpr (MODE != 2)
      __hip_atomic_store(dst_ready, SEQ, __ATOMIC_RELAXED, __HIP_MEMORY_SCOPE_AGENT);
    if constexpr (MODE != 0)
      __hip_atomic_store(src_done, SEQ / CH, __ATOMIC_RELAXED, __HIP_MEMORY_SCOPE_AGENT);
  }
}

// Grid: 96 blocks (3 layers x 32 tiles) x 512 threads. (512,2) is the PROVEN
// codegen shape: ~128 arch VGPRs, weights register-resident, zero spill.
__global__ __launch_bounds__(512, 2) void lstm_pipe(
    const float* W0i, const float* W0h, const float* b0i, const float* b0h,
    const float* W1i, const float* W1h, const float* b1i, const float* b1h,
    const float* W2i, const float* W2h, const float* b2i, const float* b2h,
    const float* x, float* y, uint32_t* ring, int* flags)
{
  const int layer = blockIdx.x >> 5;   // 0,1,2
  const int tile  = blockIdx.x & 31;
  const int b0    = tile * BT;

  __shared__ char act[2][BT * ROWB];

  uint32_t* r0 = ring;                                 // boundary 0: L0 -> L1
  uint32_t* r1 = ring + (size_t)RING * BATCH * 64;     // boundary 1: L1 -> L2

  // flags: 4 regions x 32 tiles, each flag on its own 128B line
  int* p0 = flags + (0 * NTILE + tile) * FPAD;   // ready, boundary 0
  int* p1 = flags + (1 * NTILE + tile) * FPAD;   // ready, boundary 1
  int* c0 = flags + (2 * NTILE + tile) * FPAD;   // done,  boundary 0
  int* c1 = flags + (3 * NTILE + tile) * FPAD;   // done,  boundary 1

  if (layer == 0){
    run_layer<0>(W0i, W0h, b0i, b0h, x, nullptr, r0, nullptr,
                 nullptr, nullptr, p0, c0, b0, act[0], act[1]);
  } else if (layer == 1){
    run_layer<1>(W1i, W1h, b1i, b1h, nullptr, r0, r1, nullptr,
                 p0, c0, p1, c1, b0, act[0], act[1]);
  } else {
    run_layer<2>(W2i, W2h, b2i, b2h, nullptr, r1, nullptr, y,
                 p1, c1, nullptr, nullptr, b0, act[0], act[1]);
  }
}

extern "C" void kernel_launch(void* const* d_in, const int* in_sizes, int n_in,
                              void* d_out, int out_size, void* d_ws, size_t ws_size,
                              hipStream_t stream) {
  const float* x    = (const float*)d_in[0];
  const float* Wih0 = (const float*)d_in[1];
  const float* Whh0 = (const float*)d_in[2];
  const float* bih0 = (const float*)d_in[3];
  const float* bhh0 = (const float*)d_in[4];
  const float* Wih1 = (const float*)d_in[5];
  const float* Whh1 = (const float*)d_in[6];
  const float* bih1 = (const float*)d_in[7];
  const float* bhh1 = (const float*)d_in[8];
  const float* Wih2 = (const float*)d_in[9];
  const float* Whh2 = (const float*)d_in[10];
  const float* bih2 = (const float*)d_in[11];
  const float* bhh2 = (const float*)d_in[12];

  float* out = (float*)d_out;
  uint32_t* ring = (uint32_t*)d_ws;
  const size_t ring_bytes = (size_t)2 * RING * BATCH * 64 * 4;   // 16 MiB
  int* flags = (int*)((char*)d_ws + ring_bytes);

  hipMemsetAsync(flags, 0, 4 * NTILE * FPAD * sizeof(int), stream);

  dim3 grid(3 * NTILE), block(512);
  lstm_pipe<<<grid, block, 0, stream>>>(
      Wih0, Whh0, bih0, bhh0, Wih1, Whh1, bih1, bhh1, Wih2, Whh2, bih2, bhh2,
      x, out, ring, flags);
}